// Round 5
// baseline (287.411 us; speedup 1.0000x reference)
//
#include <hip/hip_runtime.h>

// LSTM: B=16384 seqs, T=512, I=4, H=4, FC 4->1.
// Round 5: 8 lanes/seq, 131072 threads = 2048 waves = 2 waves/SIMD, with the
// pair exchange done via DPP row_ror:8 (in-VALU, ~4cyc) instead of R4's
// ds_swizzle (LDS pipe, ~100+cyc in the serial per-step chain — R4's 590
// cyc/step = chain-bound regression despite 2x TLP).
// Wave layout per 16-lane row: pos0-7 = (i,f)-pair of 2 seqs x 4 units,
// pos8-15 = (g,o)-pair of the same; quad_perm broadcasts h within unit-quads,
// row_ror:8 swaps pair halves (lane l ^ 8 within the row).
// Nonlinearities: exp2+rcp (issue-minimal; R3 proved rational tanh loses).

#define CH 4  // x double-buffer chunk (small enough to stay in VGPRs)

typedef float v2f __attribute__((ext_vector_type(2)));

__device__ __forceinline__ v2f pk_fma(v2f a, v2f b, v2f c) {
    return __builtin_elementwise_fma(a, b, c);
}

// DPP quad_perm lane-xor within aligned quads: xor1=0xB1, xor2=0x4E, xor3=0x1B
// DPP row_ror:8 = 0x128: lane i reads lane (i+8)%16 within its 16-lane row,
// i.e. exactly i^8.
template <int CTRL>
__device__ __forceinline__ float dpp_mov(float v) {
    int r = __builtin_amdgcn_mov_dpp(__float_as_int(v), CTRL, 0xF, 0xF, true);
    return __int_as_float(r);
}

__device__ __forceinline__ float fast_tanh(float x) {
    float e = __builtin_amdgcn_exp2f(-2.88539008f * x);   // exp(-2x)
    float r = __builtin_amdgcn_rcpf(1.0f + e);
    return fmaf(2.0f, r, -1.0f);
}

__global__ __launch_bounds__(256) void lstm_h4_kernel(
    const float* __restrict__ X,
    const float* __restrict__ W_ih,
    const float* __restrict__ W_hh,
    const float* __restrict__ b_ih,
    const float* __restrict__ b_hh,
    const float* __restrict__ W_fc,
    const float* __restrict__ b_fc,
    float* __restrict__ out,
    int B, int T)
{
    int gid  = blockIdx.x * blockDim.x + threadIdx.x;
    int lane = gid & 63;
    int row  = lane >> 4;          // 16-lane row within wave
    int pos  = lane & 15;
    int pair = pos >> 3;           // 0 -> (i,f) rows; 1 -> (g,o) rows
    int j    = pos & 3;            // hidden unit
    // sequence: 8 per wave = 2 per row
    int b = (gid >> 6) * 8 + (row << 1) + ((pos >> 2) & 1);
    if (b >= B) return;

    // Gate rows (PyTorch): 0-3=i, 4-7=f, 8-11=g, 12-15=o.
    int r0 = pair ? (8 + j) : (0 + j);
    int r1 = pair ? (12 + j) : (4 + j);
    v2f wih[4], whh[4], bias;
#pragma unroll
    for (int k = 0; k < 4; ++k) {
        wih[k] = (v2f){W_ih[r0 * 4 + k], W_ih[r1 * 4 + k]};
        int kc = j ^ k;            // h from quad-xor-k lane is h_{j^k}
        whh[k] = (v2f){W_hh[r0 * 4 + kc], W_hh[r1 * 4 + kc]};
    }
    bias = (v2f){b_ih[r0] + b_hh[r0], b_ih[r1] + b_hh[r1]};

    // y = svec * rcp(1 + exp2(mvec*u)) + tvec
    //   sigmoid: m=-log2e, s=1, t=0 ; tanh: m=-2log2e, s=2, t=-1
    const float L = 1.44269504f;
    const v2f mvec = pair ? (v2f){-2.0f * L, -L} : (v2f){-L, -L};
    const v2f svec = pair ? (v2f){2.0f, 1.0f}    : (v2f){1.0f, 1.0f};
    const v2f tvec = pair ? (v2f){-1.0f, 0.0f}   : (v2f){0.0f, 0.0f};

    const float4* __restrict__ xp = (const float4*)X + (size_t)b * T;

    float h = 0.0f, c = 0.0f;

    float4 cur[CH], nxt[CH];
#pragma unroll
    for (int i = 0; i < CH; ++i) cur[i] = xp[i];

    for (int tc = 0; tc < T; tc += CH) {
        if (tc + CH < T) {
#pragma unroll
            for (int i = 0; i < CH; ++i) nxt[i] = xp[tc + CH + i];
        }
#pragma unroll
        for (int i = 0; i < CH; ++i) {
            float4 x = cur[i];
            // h broadcast within unit-quad
            float h1 = dpp_mov<0xB1>(h);
            float h2 = dpp_mov<0x4E>(h);
            float h3 = dpp_mov<0x1B>(h);
            // x path (independent of recurrence — fills stall slots)
            v2f u = bias;
            u = pk_fma(wih[0], (v2f){x.x, x.x}, u);
            u = pk_fma(wih[1], (v2f){x.y, x.y}, u);
            u = pk_fma(wih[2], (v2f){x.z, x.z}, u);
            u = pk_fma(wih[3], (v2f){x.w, x.w}, u);
            // h path (tree, depth 3)
            v2f ta = pk_fma(whh[0], (v2f){h, h}, u);
            v2f tb = pk_fma(whh[2], (v2f){h2, h2}, whh[3] * (v2f){h3, h3});
            u = pk_fma(whh[1], (v2f){h1, h1}, ta) + tb;
            // own gate pair
            v2f a = u * mvec;
            v2f e = (v2f){__builtin_amdgcn_exp2f(a.x),
                          __builtin_amdgcn_exp2f(a.y)};
            v2f d = e + (v2f){1.0f, 1.0f};
            v2f r = (v2f){__builtin_amdgcn_rcpf(d.x),
                          __builtin_amdgcn_rcpf(d.y)};
            v2f own = pk_fma(svec, r, tvec);
            // exchange with partner lane (pos ^ 8) — pure VALU DPP
            v2f rcv = (v2f){dpp_mov<0x128>(own.x), dpp_mov<0x128>(own.y)};
            // {own,rcv} = {(i,f),(g,o)} in pair order; both halves update
            // c,h bit-identically (i*g commutes).
            float fg = pair ? rcv.y : own.y;
            float og = pair ? own.y : rcv.y;
            float ig = own.x * rcv.x;
            c = fmaf(fg, c, ig);
            h = og * fast_tanh(c);
        }
#pragma unroll
        for (int i = 0; i < CH; ++i) cur[i] = nxt[i];
    }

    // out[b] = sum_j h_j * W_fc[j] + b_fc  (quad reduction; pair-0 unit-0 writes)
    float partial = h * W_fc[j];
    partial += dpp_mov<0xB1>(partial);
    partial += dpp_mov<0x4E>(partial);
    if (pair == 0 && j == 0) out[b] = partial + b_fc[0];
}

extern "C" void kernel_launch(void* const* d_in, const int* in_sizes, int n_in,
                              void* d_out, int out_size, void* d_ws, size_t ws_size,
                              hipStream_t stream) {
    const float* X    = (const float*)d_in[0];
    const float* W_ih = (const float*)d_in[1];
    const float* W_hh = (const float*)d_in[2];
    const float* b_ih = (const float*)d_in[3];
    const float* b_hh = (const float*)d_in[4];
    const float* W_fc = (const float*)d_in[5];
    const float* b_fc = (const float*)d_in[6];
    float* out = (float*)d_out;

    int B = out_size;                       // 16384
    int T = in_sizes[0] / (B * 4);          // 512 (I=4)

    int threads = B * 8;
    dim3 block(256);
    dim3 grid((threads + 255) / 256);
    lstm_h4_kernel<<<grid, block, 0, stream>>>(X, W_ih, W_hh, b_ih, b_hh,
                                               W_fc, b_fc, out, B, T);
}

// Round 6
// 257.026 us; speedup vs baseline: 1.1182x; 1.1182x over previous
//
#include <hip/hip_runtime.h>

// LSTM: B=16384 seqs, T=512, I=4, H=4, FC 4->1.
// Round 6: R2's 4-lane/seq compute core (lowest measured issue: ~206
// cyc/wave-step) + X staged through LDS with async global_load_lds.
// R2-R5's VGPR counts (36-72) prove the compiler collapsed every
// register double-buffer and sank loads to just-before-use -> exposed
// HBM latency was the ~300 cyc/step stall all along. global_load_lds
// completion is tracked by vmcnt (drained at one __syncthreads per
// 8-step chunk, issued a full chunk ahead) -- the compiler can't sink it.
// Block = 64 threads = 1 wave -> barrier is wave-private (no coupling).
// LDS layout dt-major: float4 slot (dt*16 + seq) => ds_read_b128 is
// quad-broadcast + 2-way bank alias (free, m136). 2 x 2KB buffers.

#define CH 8            // timesteps per staged chunk
#define SPW 16          // sequences per wave (64 lanes / 4 lanes-per-seq)

typedef float v2f __attribute__((ext_vector_type(2)));

typedef __attribute__((address_space(1))) const unsigned int* gas_u32p;
typedef __attribute__((address_space(3))) unsigned int* las_u32p;

__device__ __forceinline__ void stage16(const void* g, void* lds_base) {
    // lane writes 16B to lds_base + lane*16 (wave-uniform base, HW-scattered)
    __builtin_amdgcn_global_load_lds((gas_u32p)g, (las_u32p)lds_base, 16, 0, 0);
}

__device__ __forceinline__ v2f pk_fma(v2f a, v2f b, v2f c) {
    return __builtin_elementwise_fma(a, b, c);
}

// DPP quad_perm lane-xor within aligned quads: xor1=0xB1, xor2=0x4E, xor3=0x1B
template <int CTRL>
__device__ __forceinline__ float quad_xor(float v) {
    int r = __builtin_amdgcn_mov_dpp(__float_as_int(v), CTRL, 0xF, 0xF, true);
    return __int_as_float(r);
}

__device__ __forceinline__ float fast_tanh(float x) {
    float e = __builtin_amdgcn_exp2f(-2.88539008f * x);   // exp(-2x)
    float r = __builtin_amdgcn_rcpf(1.0f + e);
    return fmaf(2.0f, r, -1.0f);
}

__global__ __launch_bounds__(64) void lstm_h4_kernel(
    const float* __restrict__ X,
    const float* __restrict__ W_ih,
    const float* __restrict__ W_hh,
    const float* __restrict__ b_ih,
    const float* __restrict__ b_hh,
    const float* __restrict__ W_fc,
    const float* __restrict__ b_fc,
    float* __restrict__ out,
    int B, int T)
{
    int lane = threadIdx.x;            // 0..63
    int seqbase = blockIdx.x * SPW;    // grid covers B exactly
    int j  = lane & 3;                 // hidden unit
    int sl = lane >> 2;                // local sequence 0..15
    int b  = seqbase + sl;

    __shared__ float4 lbuf[2][CH * SPW];   // 2 x 2KB, wave-private

    const float4* __restrict__ x4 = (const float4*)X;

    // Gate rows (PyTorch): 0-3=i, 4-7=f, 8-11=g, 12-15=o.
    // Pair 0 = (i_j, f_j); pair 1 = (g_j, o_j). whh_*[k] multiplies h from
    // quad lane j^k -> column (j^k).
    v2f wih0[4], wih1[4], whh0[4], whh1[4], bias0, bias1;
    {
        int rI = 0 * 4 + j, rF = 1 * 4 + j, rG = 2 * 4 + j, rO = 3 * 4 + j;
#pragma unroll
        for (int k = 0; k < 4; ++k) {
            wih0[k] = (v2f){W_ih[rI * 4 + k], W_ih[rF * 4 + k]};
            wih1[k] = (v2f){W_ih[rG * 4 + k], W_ih[rO * 4 + k]};
            int kc = j ^ k;
            whh0[k] = (v2f){W_hh[rI * 4 + kc], W_hh[rF * 4 + kc]};
            whh1[k] = (v2f){W_hh[rG * 4 + kc], W_hh[rO * 4 + kc]};
        }
        bias0 = (v2f){b_ih[rI] + b_hh[rI], b_ih[rF] + b_hh[rF]};
        bias1 = (v2f){b_ih[rG] + b_hh[rG], b_ih[rO] + b_hh[rO]};
    }

    // y = s * rcp(1 + exp2(m*x)) + t ; sigmoid m=-log2e, tanh m=-2log2e
    const v2f m_if = (v2f){-1.44269504f, -1.44269504f};
    const v2f m_go = (v2f){-2.88539008f, -1.44269504f};   // (tanh, sigmoid)
    const v2f s_go = (v2f){2.0f, 1.0f};
    const v2f t_go = (v2f){-1.0f, 0.0f};

    // Stage chunk starting at time tt into lbuf[buf].
    // Flat slot f in [0,128): dt = f>>4, seq = f&15  (dt-major).
    auto stage_chunk = [&](int tt, int bf) {
#pragma unroll
        for (int n = 0; n < 2; ++n) {
            int f   = n * 64 + lane;
            int dts = f >> 4;
            int ss  = f & 15;
            const float4* g = x4 + (size_t)(seqbase + ss) * T + (tt + dts);
            stage16((const void*)g, (void*)&lbuf[bf][n * 64]);
        }
    };

    stage_chunk(0, 0);

    float h = 0.0f, c = 0.0f;
    int buf = 0;

    for (int tc = 0; tc < T; tc += CH) {
        __syncthreads();   // vmcnt(0): buffer staged last iter (or prologue) ready
        if (tc + CH < T) stage_chunk(tc + CH, buf ^ 1);
#pragma unroll
        for (int dt = 0; dt < CH; ++dt) {
            float4 x = lbuf[buf][dt * 16 + sl];   // quad-broadcast ds_read_b128
            // x path (independent of recurrence)
            v2f p0 = bias0, p1 = bias1;
            p0 = pk_fma(wih0[0], (v2f){x.x, x.x}, p0);
            p1 = pk_fma(wih1[0], (v2f){x.x, x.x}, p1);
            p0 = pk_fma(wih0[1], (v2f){x.y, x.y}, p0);
            p1 = pk_fma(wih1[1], (v2f){x.y, x.y}, p1);
            p0 = pk_fma(wih0[2], (v2f){x.z, x.z}, p0);
            p1 = pk_fma(wih1[2], (v2f){x.z, x.z}, p1);
            p0 = pk_fma(wih0[3], (v2f){x.w, x.w}, p0);
            p1 = pk_fma(wih1[3], (v2f){x.w, x.w}, p1);
            // h path (quad broadcast + depth-3 tree)
            float h1 = quad_xor<0xB1>(h);
            float h2 = quad_xor<0x4E>(h);
            float h3 = quad_xor<0x1B>(h);
            v2f hb0 = (v2f){h,  h},  hb1 = (v2f){h1, h1};
            v2f hb2 = (v2f){h2, h2}, hb3 = (v2f){h3, h3};
            v2f u0a = pk_fma(whh0[0], hb0, p0);
            v2f u0b = pk_fma(whh0[2], hb2, whh0[3] * hb3);
            v2f u1a = pk_fma(whh1[0], hb0, p1);
            v2f u1b = pk_fma(whh1[2], hb2, whh1[3] * hb3);
            v2f u0 = pk_fma(whh0[1], hb1, u0a) + u0b;
            v2f u1 = pk_fma(whh1[1], hb1, u1a) + u1b;
            // nonlinearities (exp2 + rcp — measured issue-minimal)
            v2f a0 = u0 * m_if;
            v2f a1 = u1 * m_go;
            v2f e0 = (v2f){__builtin_amdgcn_exp2f(a0.x),
                           __builtin_amdgcn_exp2f(a0.y)};
            v2f e1 = (v2f){__builtin_amdgcn_exp2f(a1.x),
                           __builtin_amdgcn_exp2f(a1.y)};
            v2f d0 = e0 + (v2f){1.0f, 1.0f};
            v2f d1 = e1 + (v2f){1.0f, 1.0f};
            float ig = __builtin_amdgcn_rcpf(d0.x);
            float fg = __builtin_amdgcn_rcpf(d0.y);
            v2f r1 = (v2f){__builtin_amdgcn_rcpf(d1.x),
                           __builtin_amdgcn_rcpf(d1.y)};
            v2f go = pk_fma(s_go, r1, t_go);   // (tanh g, sigmoid o)
            c = fmaf(fg, c, ig * go.x);
            h = go.y * fast_tanh(c);
        }
        buf ^= 1;
    }

    // out[b] = sum_j h_j * W_fc[j] + b_fc  (quad reduction)
    float partial = h * W_fc[j];
    partial += quad_xor<0xB1>(partial);
    partial += quad_xor<0x4E>(partial);
    if (j == 0) out[b] = partial + b_fc[0];
}

extern "C" void kernel_launch(void* const* d_in, const int* in_sizes, int n_in,
                              void* d_out, int out_size, void* d_ws, size_t ws_size,
                              hipStream_t stream) {
    const float* X    = (const float*)d_in[0];
    const float* W_ih = (const float*)d_in[1];
    const float* W_hh = (const float*)d_in[2];
    const float* b_ih = (const float*)d_in[3];
    const float* b_hh = (const float*)d_in[4];
    const float* W_fc = (const float*)d_in[5];
    const float* b_fc = (const float*)d_in[6];
    float* out = (float*)d_out;

    int B = out_size;                       // 16384
    int T = in_sizes[0] / (B * 4);          // 512 (I=4)

    dim3 block(64);
    dim3 grid(B / SPW);                     // 1024 blocks = 1 wave each
    lstm_h4_kernel<<<grid, block, 0, stream>>>(X, W_ih, W_hh, b_ih, b_hh,
                                               W_fc, b_fc, out, B, T);
}